// Round 6
// baseline (530.575 us; speedup 1.0000x reference)
//
#include <hip/hip_runtime.h>

#define CH 128
#define OUTC 10
#define NB 256            // buckets (dst >> 9), only ceil(N/512) used
#define BCAP 10240        // per-bucket pair capacity (avg ~8192, >22 sigma margin)
#define PCHUNK 2048       // edges per partition block
#define PQ2 132           // LDS pitch in bf16 (dword stride 66 -> 2-way bank alias = free)
#define FBM 64            // rows per layer block

typedef __attribute__((ext_vector_type(8))) short short8;
typedef __attribute__((ext_vector_type(4))) short short4v;
typedef __attribute__((ext_vector_type(16))) float f32x16;
typedef __attribute__((ext_vector_type(2))) float f32x2;

// ---------------------------------------------------------------- helpers

__device__ inline unsigned short f2bf(float f) {
    unsigned u = __builtin_bit_cast(unsigned, f);
    u += 0x7fffu + ((u >> 16) & 1u);   // RNE
    return (unsigned short)(u >> 16);
}
__device__ inline float bflo(unsigned u) { return __builtin_bit_cast(float, u << 16); }
__device__ inline float bfhi(unsigned u) { return __builtin_bit_cast(float, u & 0xffff0000u); }

// packed bf16 pair -> f32x2 (lshl / and, then one packed add on the consumer)
__device__ inline f32x2 bf2(unsigned u) {
    return (f32x2){__builtin_bit_cast(float, u << 16),
                   __builtin_bit_cast(float, u & 0xffff0000u)};
}

__device__ inline void acc4(f32x2* a, const uint2& v) {
    a[0] += bf2(v.x);
    a[1] += bf2(v.y);
}

// ---------------------------------------------------------------- mega prep: edge partition + x->bf16 + w-swizzle + pooled zero

struct WPtrs { const float* s[6]; unsigned short* d[6]; };

__global__ void prep_part_kernel(const int* __restrict__ src, const int* __restrict__ dst,
                                 int* __restrict__ bucketCnt, unsigned* __restrict__ pairs, int E,
                                 int nPartBlk,
                                 const float4* __restrict__ x4, uint2* __restrict__ xb, int n4,
                                 int nConvBlk, WPtrs p,
                                 uint4* __restrict__ pooled4, int nPooled4) {
    __shared__ int hist[NB];
    __shared__ int base[NB];
    __shared__ int cur[NB];
    int tid = threadIdx.x;   // 256
    int b = blockIdx.x;

    if (b < nPartBlk) {
        int e0 = b * PCHUNK;
        hist[tid] = 0;
        __syncthreads();
        #pragma unroll
        for (int i = 0; i < PCHUNK / 256; ++i) {
            int e = e0 + tid + i * 256;
            if (e < E) atomicAdd(&hist[dst[e] >> 9], 1);
        }
        __syncthreads();
        {
            int c = hist[tid];
            base[tid] = (c > 0) ? atomicAdd(&bucketCnt[tid], c) : 0;
            cur[tid] = 0;
        }
        __syncthreads();
        #pragma unroll
        for (int i = 0; i < PCHUNK / 256; ++i) {
            int e = e0 + tid + i * 256;
            if (e < E) {
                int d = dst[e];
                int bkt = d >> 9;
                int pos = base[bkt] + atomicAdd(&cur[bkt], 1);
                if (pos < BCAP)
                    pairs[bkt * BCAP + pos] = ((unsigned)(d & 511) << 17) | (unsigned)src[e];
            }
        }
    } else if (b < nPartBlk + nConvBlk) {
        int i = (b - nPartBlk) * 256 + tid;
        if (i < n4) {
            float4 v = x4[i];
            uint2 o;
            o.x = (unsigned)f2bf(v.x) | ((unsigned)f2bf(v.y) << 16);
            o.y = (unsigned)f2bf(v.z) | ((unsigned)f2bf(v.w) << 16);
            xb[i] = o;
        }
    } else if (b < nPartBlk + nConvBlk + 384) {
        int bb = b - nPartBlk - nConvBlk;  // 0..383
        int m = bb >> 6;                   // matrix 0..5
        int i = (bb & 63) * 256 + tid;     // 0..16383
        int j = i & 7;
        int l = (i >> 3) & 63;
        int k0 = (i >> 9) & 7;
        int ct = (i >> 12) & 3;
        int k = k0 * 16 + ((l >> 5) << 3) + j;
        int nn = ct * 32 + (l & 31);
        p.d[m][i] = f2bf(p.s[m][k * CH + nn]);
    } else {
        int i = (b - nPartBlk - nConvBlk - 384) * 256 + tid;
        if (i < nPooled4) pooled4[i] = make_uint4(0, 0, 0, 0);
    }
}

// ---------------------------------------------------------------- CSR build (self-scans bucket counts)

__launch_bounds__(512)
__global__ void build_csr_kernel(const unsigned* __restrict__ pairs, const int* __restrict__ bucketCnt,
                                 int* __restrict__ offs, int* __restrict__ csr, int N) {
    __shared__ int bsm[NB];
    __shared__ int ldeg[512];
    __shared__ int s0[512], s1[512];
    __shared__ int lexc[512];
    __shared__ int lcur[512];
    __shared__ int lcsr[BCAP];

    int b = blockIdx.x;
    int node0 = b << 9;
    if (node0 >= N) return;
    int nLocal = min(512, N - node0);
    int tid = threadIdx.x;   // 512

    if (tid < NB) bsm[tid] = bucketCnt[tid];
    __syncthreads();
    for (int off = 1; off < NB; off <<= 1) {
        int t = 0;
        if (tid < NB) t = (tid >= off) ? bsm[tid - off] : 0;
        __syncthreads();
        if (tid < NB) bsm[tid] += t;
        __syncthreads();
    }
    int cnt = min(bucketCnt[b], BCAP);
    int gbase = bsm[b] - bucketCnt[b];

    ldeg[tid] = 0;
    __syncthreads();
    for (int i = tid; i < cnt; i += 512)
        atomicAdd(&ldeg[pairs[b * BCAP + i] >> 17], 1);
    __syncthreads();

    s0[tid] = ldeg[tid];
    __syncthreads();
    int* sp = s0; int* dp = s1;
    for (int off = 1; off < 512; off <<= 1) {
        dp[tid] = sp[tid] + ((tid >= off) ? sp[tid - off] : 0);
        __syncthreads();
        int* t = sp; sp = dp; dp = t;
    }
    {
        int ex = sp[tid] - ldeg[tid];
        lexc[tid] = ex;
        lcur[tid] = ex;
    }
    __syncthreads();

    for (int i = tid; i < cnt; i += 512) {
        unsigned w = pairs[b * BCAP + i];
        int ppos = atomicAdd(&lcur[w >> 17], 1);
        lcsr[ppos] = (int)(w & 0x1ffffu);
    }
    __syncthreads();

    for (int i = tid; i < cnt; i += 512) csr[gbase + i] = lcsr[i];
    for (int i = tid; i < nLocal; i += 512) offs[node0 + i] = gbase + lexc[i];
    if (tid == 0 && node0 + nLocal == N) offs[N] = gbase + cnt;
}

// ---------------------------------------------------------------- gather kernel (channel-quarter sliced, XCD-aware)
// R6: FETCH (187MB) == 8 XCDs x whole h (23MB) at ~330 GB/s per-XCD fill ==
// the wall. Slice channels into quarters (32 ch = 64 B/row) and lay out the
// grid so blockIdx%8 (HW round-robin XCD assignment) maps XCD pair {2q,2q+1}
// -> quarter q. Each XCD then fills only ~6.4MB of h (+ csr for half the dst
// blocks) instead of 23MB. Mapping is a perf heuristic only: any fixed-offset
// round-robin still gives one quarter per XCD; correctness never depends on it.
// Per-channel accumulation order (self, then ascending edges, 4-batch + tail)
// is identical to the fused kernel -> bit-exact z.

__launch_bounds__(512)
__global__ void gather_q_kernel(const uint2* __restrict__ h2,
                                const int* __restrict__ offs, const int* __restrict__ csr,
                                uint2* __restrict__ z2, int n) {
    int b = blockIdx.x;
    int r = b & 7;
    int quarter = r >> 1;
    int dstBlk = (b >> 3) * 2 + (r & 1);
    int gl = threadIdx.x & 7;       // 8 lanes x 8B = one 32-ch quarter slice
    int grp = threadIdx.x >> 3;     // 0..63 — one row per group, all concurrent
    int node = dstBlk * FBM + grp;
    if (node >= n) return;
    int cb = quarter * 8 + gl;      // uint2 index within the 32-uint2 row

    int beg = offs[node], end = offs[node + 1];
    f32x2 a[2];
    {
        uint2 s = h2[node * 32 + cb];
        a[0] = bf2(s.x); a[1] = bf2(s.y);
    }
    int e = beg;
    for (; e + 4 <= end; e += 4) {
        int i0 = csr[e], i1 = csr[e + 1], i2 = csr[e + 2], i3 = csr[e + 3];
        uint2 v0 = h2[i0 * 32 + cb];
        uint2 v1 = h2[i1 * 32 + cb];
        uint2 v2 = h2[i2 * 32 + cb];
        uint2 v3 = h2[i3 * 32 + cb];
        acc4(a, v0); acc4(a, v1); acc4(a, v2); acc4(a, v3);
    }
    for (; e < end; ++e) {
        uint2 v = h2[csr[e] * 32 + cb];
        acc4(a, v);
    }
    uint2 o;
    o.x = (unsigned)f2bf(a[0][0]) | ((unsigned)f2bf(a[0][1]) << 16);
    o.y = (unsigned)f2bf(a[1][0]) | ((unsigned)f2bf(a[1][1]) << 16);
    z2[node * 32 + cb] = o;
}

// ---------------------------------------------------------------- MLP kernel: z (global bf16) -> LDS -> MFMA MLP -> write | pool
// Same MFMA structure as the fused kernel; z now staged from HBM (coalesced).

template <int RELU, int POOL>
__launch_bounds__(512)
__global__ void mlp_kernel(const uint2* __restrict__ z2g,
                           const unsigned short* __restrict__ w1s, const float* __restrict__ b1,
                           const unsigned short* __restrict__ w2s, const float* __restrict__ b2,
                           unsigned short* __restrict__ hout,
                           const int* __restrict__ batch, float* __restrict__ pooled,
                           int n) {
    __shared__ __align__(16) unsigned short zs[FBM * PQ2];   // 16.9 KB

    int tid = threadIdx.x;
    int row0 = blockIdx.x * FBM;

    // stage z tile: 64 rows x 32 uint2, 4 per thread, coalesced
    for (int i = tid; i < FBM * 32; i += 512) {
        int rr = i >> 5, cc = i & 31;
        int row = row0 + rr;
        uint2 v = make_uint2(0, 0);
        if (row < n) v = z2g[row * 32 + cc];
        *(uint2*)&zs[rr * PQ2 + cc * 4] = v;
    }
    __syncthreads();

    int wv = tid >> 6;         // 0..7
    int lane = tid & 63;
    int l31 = lane & 31;
    int kh = lane >> 5;
    int rt = wv & 1;           // 2 row tiles of 32
    int ct = wv >> 1;          // 4 col tiles of 32
    int arow = rt * 32 + l31;

    // ---- matmul 1: t = relu(z @ w1 + b1)
    f32x16 acc;
    {
        float bv = b1[ct * 32 + l31];
        #pragma unroll
        for (int r = 0; r < 16; ++r) acc[r] = bv;
    }
    #pragma unroll
    for (int k0 = 0; k0 < 8; ++k0) {
        short8 afr;
        {
            short4v lo = *(const short4v*)&zs[arow * PQ2 + k0 * 16 + kh * 8];
            short4v hi = *(const short4v*)&zs[arow * PQ2 + k0 * 16 + kh * 8 + 4];
            afr = (short8){lo[0], lo[1], lo[2], lo[3], hi[0], hi[1], hi[2], hi[3]};
        }
        short8 bfr = *(const short8*)&w1s[(((ct * 8 + k0) * 64) + lane) * 8];
        acc = __builtin_amdgcn_mfma_f32_32x32x16_bf16(afr, bfr, acc, 0, 0, 0);
    }
    __syncthreads();

    #pragma unroll
    for (int reg = 0; reg < 16; ++reg) {
        int crow = (reg & 3) + 8 * (reg >> 2) + 4 * kh;
        zs[(rt * 32 + crow) * PQ2 + ct * 32 + l31] = f2bf(fmaxf(acc[reg], 0.f));
    }
    __syncthreads();

    // ---- matmul 2: h = t @ w2 + b2 [+ relu]
    {
        float bv = b2[ct * 32 + l31];
        #pragma unroll
        for (int r = 0; r < 16; ++r) acc[r] = bv;
    }
    #pragma unroll
    for (int k0 = 0; k0 < 8; ++k0) {
        short8 afr;
        {
            short4v lo = *(const short4v*)&zs[arow * PQ2 + k0 * 16 + kh * 8];
            short4v hi = *(const short4v*)&zs[arow * PQ2 + k0 * 16 + kh * 8 + 4];
            afr = (short8){lo[0], lo[1], lo[2], lo[3], hi[0], hi[1], hi[2], hi[3]};
        }
        short8 bfr = *(const short8*)&w2s[(((ct * 8 + k0) * 64) + lane) * 8];
        acc = __builtin_amdgcn_mfma_f32_32x32x16_bf16(afr, bfr, acc, 0, 0, 0);
    }
    __syncthreads();

    #pragma unroll
    for (int reg = 0; reg < 16; ++reg) {
        int crow = (reg & 3) + 8 * (reg >> 2) + 4 * kh;
        float v = acc[reg];
        if (RELU) v = fmaxf(v, 0.f);
        zs[(rt * 32 + crow) * PQ2 + ct * 32 + l31] = f2bf(v);
    }
    __syncthreads();

    if (!POOL) {
        for (int i = tid; i < FBM * 16; i += 512) {
            int r = i >> 4, c = i & 15;
            int row = row0 + r;
            if (row < n) {
                uint2 a2 = *(const uint2*)&zs[r * PQ2 + c * 8];
                uint2 b2v = *(const uint2*)&zs[r * PQ2 + c * 8 + 4];
                ((uint4*)hout)[row * 16 + c] = make_uint4(a2.x, a2.y, b2v.x, b2v.y);
            }
        }
    } else {
        // pool epilogue from LDS tile (batch sorted)
        int c2 = tid & 63;      // uint column (ch 2*c2, 2*c2+1)
        int rs = tid >> 6;      // 0..7
        float a0 = 0.f, a1 = 0.f;
        int prevg = -1;
        #pragma unroll
        for (int i = 0; i < FBM / 8; ++i) {
            int r = rs + 8 * i;
            int row = row0 + r;
            if (row >= n) break;
            int g = batch[row];
            if (g != prevg) {
                if (prevg >= 0) {
                    atomicAdd(&pooled[prevg * CH + 2 * c2], a0);
                    atomicAdd(&pooled[prevg * CH + 2 * c2 + 1], a1);
                }
                prevg = g; a0 = 0.f; a1 = 0.f;
            }
            unsigned v = *(const unsigned*)&zs[r * PQ2 + c2 * 2];
            a0 += bflo(v); a1 += bfhi(v);
        }
        if (prevg >= 0) {
            atomicAdd(&pooled[prevg * CH + 2 * c2], a0);
            atomicAdd(&pooled[prevg * CH + 2 * c2 + 1], a1);
        }
    }
}

// ---------------------------------------------------------------- final linear

__global__ void final_linear_kernel(const float* __restrict__ pooled, const float* __restrict__ lin_w,
                                    const float* __restrict__ lin_b, float* __restrict__ out) {
    int g = blockIdx.x;
    int tid = threadIdx.x;   // 128
    __shared__ float pl[CH];
    pl[tid] = pooled[g * CH + tid];
    __syncthreads();
    if (tid < OUTC) {
        float a = lin_b[tid];
        #pragma unroll 16
        for (int c = 0; c < CH; ++c) a = fmaf(pl[c], lin_w[c * OUTC + tid], a);
        out[g * OUTC + tid] = a;
    }
}

// ---------------------------------------------------------------- launch

static inline size_t aln(size_t x) { return (x + 255) & ~size_t(255); }

extern "C" void kernel_launch(void* const* d_in, const int* in_sizes, int n_in,
                              void* d_out, int out_size, void* d_ws, size_t ws_size,
                              hipStream_t stream) {
    const float* x      = (const float*)d_in[0];
    const int*   ei     = (const int*)d_in[1];
    const int*   batch  = (const int*)d_in[2];
    const float* w1[3]  = {(const float*)d_in[3], (const float*)d_in[7],  (const float*)d_in[11]};
    const float* b1[3]  = {(const float*)d_in[4], (const float*)d_in[8],  (const float*)d_in[12]};
    const float* w2[3]  = {(const float*)d_in[5], (const float*)d_in[9],  (const float*)d_in[13]};
    const float* b2[3]  = {(const float*)d_in[6], (const float*)d_in[10], (const float*)d_in[14]};
    const float* lin_w  = (const float*)d_in[15];
    const float* lin_b  = (const float*)d_in[16];
    float* out = (float*)d_out;

    int E = in_sizes[1] / 2;
    int N = in_sizes[2];
    int n_graphs = out_size / OUTC;
    const int* src = ei;
    const int* dst = ei + E;

    char* p = (char*)d_ws;
    int* bucketCnt  = (int*)p; p += aln(NB * 4);
    unsigned* pairs = (unsigned*)p; p += aln((size_t)NB * BCAP * 4);
    int* offs       = (int*)p; p += aln((size_t)(N + 1) * 4);
    int* csr        = (int*)p; p += aln((size_t)E * 4);
    unsigned short* xb = (unsigned short*)p; p += aln((size_t)N * CH * 2);
    unsigned short* hA = (unsigned short*)p; p += aln((size_t)N * CH * 2);
    unsigned short* hB = (unsigned short*)p; p += aln((size_t)N * CH * 2);
    unsigned short* zb = (unsigned short*)p; p += aln((size_t)N * CH * 2);
    float* pooled = (float*)p; p += aln((size_t)n_graphs * CH * 4);
    unsigned short* wt[6];
    for (int i = 0; i < 6; ++i) { wt[i] = (unsigned short*)p; p += aln((size_t)CH * CH * 2); }
    (void)ws_size; (void)n_in;

    // bucketCnt must be zero before partition blocks run
    hipMemsetAsync(bucketCnt, 0, NB * 4, stream);

    // mega-prep: partition + convert x + swizzle weights + zero pooled
    int n4 = N * CH / 4;
    int nConvBlk = (n4 + 255) / 256;
    int nPartBlk = (E + PCHUNK - 1) / PCHUNK;
    int nPooled4 = n_graphs * CH / 4;
    int nZeroBlk = (nPooled4 + 255) / 256;
    WPtrs wp;
    for (int l = 0; l < 3; ++l) {
        wp.s[2 * l] = w1[l];     wp.d[2 * l] = wt[2 * l];
        wp.s[2 * l + 1] = w2[l]; wp.d[2 * l + 1] = wt[2 * l + 1];
    }
    prep_part_kernel<<<nPartBlk + nConvBlk + 384 + nZeroBlk, 256, 0, stream>>>(
        src, dst, bucketCnt, pairs, E, nPartBlk,
        (const float4*)x, (uint2*)xb, n4, nConvBlk, wp,
        (uint4*)pooled, nPooled4);

    build_csr_kernel<<<NB, 512, 0, stream>>>(pairs, bucketCnt, offs, csr, N);

    int fblk = (N + FBM - 1) / FBM;
    int nPair = (fblk + 1) / 2;          // dst-block pairs; grid = nPair * 8
    int gblk = nPair * 8;

    const unsigned short* hin[3] = {xb, hA, hB};
    unsigned short* hout[3] = {hA, hB, nullptr};

    for (int l = 0; l < 3; ++l) {
        gather_q_kernel<<<gblk, 512, 0, stream>>>(
            (const uint2*)hin[l], offs, csr, (uint2*)zb, N);
        if (l < 2) {
            mlp_kernel<1, 0><<<fblk, 512, 0, stream>>>(
                (const uint2*)zb, wt[2 * l], b1[l], wt[2 * l + 1], b2[l],
                hout[l], batch, pooled, N);
        } else {
            mlp_kernel<0, 1><<<fblk, 512, 0, stream>>>(
                (const uint2*)zb, wt[2 * l], b1[l], wt[2 * l + 1], b2[l],
                nullptr, batch, pooled, N);
        }
    }

    final_linear_kernel<<<n_graphs, CH, 0, stream>>>(pooled, lin_w, lin_b, out);
}

// Round 7
// 384.267 us; speedup vs baseline: 1.3807x; 1.3807x over previous
//
#include <hip/hip_runtime.h>

#define CH 128
#define OUTC 10
#define NB 256            // buckets (dst >> 9), only ceil(N/512) used
#define BCAP 10240        // per-bucket pair capacity (avg ~8192, >22 sigma margin)
#define PCHUNK 2048       // edges per partition block
#define PQ2 132           // LDS pitch in bf16 (dword stride 66 -> 2-way bank alias = free)
#define FBM 64            // rows per fused-layer block

typedef __attribute__((ext_vector_type(8))) short short8;
typedef __attribute__((ext_vector_type(4))) short short4v;
typedef __attribute__((ext_vector_type(16))) float f32x16;
typedef __attribute__((ext_vector_type(2))) float f32x2;

// ---------------------------------------------------------------- helpers

__device__ inline unsigned short f2bf(float f) {
    unsigned u = __builtin_bit_cast(unsigned, f);
    u += 0x7fffu + ((u >> 16) & 1u);   // RNE
    return (unsigned short)(u >> 16);
}
__device__ inline float bflo(unsigned u) { return __builtin_bit_cast(float, u << 16); }
__device__ inline float bfhi(unsigned u) { return __builtin_bit_cast(float, u & 0xffff0000u); }

// packed bf16 pair -> f32x2 (lshl / and, then one packed add on the consumer)
__device__ inline f32x2 bf2(unsigned u) {
    return (f32x2){__builtin_bit_cast(float, u << 16),
                   __builtin_bit_cast(float, u & 0xffff0000u)};
}

__device__ inline void acc8(f32x2* a, const uint4& v) {
    a[0] += bf2(v.x);
    a[1] += bf2(v.y);
    a[2] += bf2(v.z);
    a[3] += bf2(v.w);
}

// ---------------------------------------------------------------- mega prep: edge partition + x->bf16 + w-swizzle + pooled zero

struct WPtrs { const float* s[6]; unsigned short* d[6]; };

__global__ void prep_part_kernel(const int* __restrict__ src, const int* __restrict__ dst,
                                 int* __restrict__ bucketCnt, unsigned* __restrict__ pairs, int E,
                                 int nPartBlk,
                                 const float4* __restrict__ x4, uint2* __restrict__ xb, int n4,
                                 int nConvBlk, WPtrs p,
                                 uint4* __restrict__ pooled4, int nPooled4) {
    __shared__ int hist[NB];
    __shared__ int base[NB];
    __shared__ int cur[NB];
    int tid = threadIdx.x;   // 256
    int b = blockIdx.x;

    if (b < nPartBlk) {
        int e0 = b * PCHUNK;
        hist[tid] = 0;
        __syncthreads();
        #pragma unroll
        for (int i = 0; i < PCHUNK / 256; ++i) {
            int e = e0 + tid + i * 256;
            if (e < E) atomicAdd(&hist[dst[e] >> 9], 1);
        }
        __syncthreads();
        {
            int c = hist[tid];
            base[tid] = (c > 0) ? atomicAdd(&bucketCnt[tid], c) : 0;
            cur[tid] = 0;
        }
        __syncthreads();
        #pragma unroll
        for (int i = 0; i < PCHUNK / 256; ++i) {
            int e = e0 + tid + i * 256;
            if (e < E) {
                int d = dst[e];
                int bkt = d >> 9;
                int pos = base[bkt] + atomicAdd(&cur[bkt], 1);
                if (pos < BCAP)
                    pairs[bkt * BCAP + pos] = ((unsigned)(d & 511) << 17) | (unsigned)src[e];
            }
        }
    } else if (b < nPartBlk + nConvBlk) {
        int i = (b - nPartBlk) * 256 + tid;
        if (i < n4) {
            float4 v = x4[i];
            uint2 o;
            o.x = (unsigned)f2bf(v.x) | ((unsigned)f2bf(v.y) << 16);
            o.y = (unsigned)f2bf(v.z) | ((unsigned)f2bf(v.w) << 16);
            xb[i] = o;
        }
    } else if (b < nPartBlk + nConvBlk + 384) {
        int bb = b - nPartBlk - nConvBlk;  // 0..383
        int m = bb >> 6;                   // matrix 0..5
        int i = (bb & 63) * 256 + tid;     // 0..16383
        int j = i & 7;
        int l = (i >> 3) & 63;
        int k0 = (i >> 9) & 7;
        int ct = (i >> 12) & 3;
        int k = k0 * 16 + ((l >> 5) << 3) + j;
        int nn = ct * 32 + (l & 31);
        p.d[m][i] = f2bf(p.s[m][k * CH + nn]);
    } else {
        int i = (b - nPartBlk - nConvBlk - 384) * 256 + tid;
        if (i < nPooled4) pooled4[i] = make_uint4(0, 0, 0, 0);
    }
}

// ---------------------------------------------------------------- CSR build (self-scans bucket counts)
// R7 addition: emit a degree-balanced pairing permutation per 64-row fused
// block. Fused gather time is max over row-chains (Poisson(16) degrees,
// max of 32 sums >> mean) amplified by the block barrier — R5 vs R6 showed
// the barrier-coupled straggler costs ~1.5x fabric throughput. Pairing rank
// g with rank 63-g makes per-group work ~uniform so all waves hit the
// barrier together. Per-node accumulation order unchanged -> bit-exact.

__launch_bounds__(512)
__global__ void build_csr_kernel(const unsigned* __restrict__ pairs, const int* __restrict__ bucketCnt,
                                 int* __restrict__ offs, int* __restrict__ csr,
                                 int* __restrict__ perm, int N) {
    __shared__ int bsm[NB];
    __shared__ int ldeg[512];
    __shared__ int s0[512], s1[512];
    __shared__ int lexc[512];
    __shared__ int lcur[512];
    __shared__ int skey[512];
    __shared__ int lcsr[BCAP];

    int b = blockIdx.x;
    int node0 = b << 9;
    if (node0 >= N) return;
    int nLocal = min(512, N - node0);
    int tid = threadIdx.x;   // 512

    if (tid < NB) bsm[tid] = bucketCnt[tid];
    __syncthreads();
    for (int off = 1; off < NB; off <<= 1) {
        int t = 0;
        if (tid < NB) t = (tid >= off) ? bsm[tid - off] : 0;
        __syncthreads();
        if (tid < NB) bsm[tid] += t;
        __syncthreads();
    }
    int cnt = min(bucketCnt[b], BCAP);
    int gbase = bsm[b] - bucketCnt[b];

    ldeg[tid] = 0;
    __syncthreads();
    for (int i = tid; i < cnt; i += 512)
        atomicAdd(&ldeg[pairs[b * BCAP + i] >> 17], 1);
    __syncthreads();

    s0[tid] = ldeg[tid];
    __syncthreads();
    int* sp = s0; int* dp = s1;
    for (int off = 1; off < 512; off <<= 1) {
        dp[tid] = sp[tid] + ((tid >= off) ? sp[tid - off] : 0);
        __syncthreads();
        int* t = sp; sp = dp; dp = t;
    }
    {
        int ex = sp[tid] - ldeg[tid];
        lexc[tid] = ex;
        lcur[tid] = ex;
    }
    __syncthreads();

    for (int i = tid; i < cnt; i += 512) {
        unsigned w = pairs[b * BCAP + i];
        int ppos = atomicAdd(&lcur[w >> 17], 1);
        lcsr[ppos] = (int)(w & 0x1ffffu);
    }
    __syncthreads();

    for (int i = tid; i < cnt; i += 512) csr[gbase + i] = lcsr[i];
    for (int i = tid; i < nLocal; i += 512) offs[node0 + i] = gbase + lexc[i];
    if (tid == 0 && node0 + nLocal == N) offs[N] = gbase + cnt;

    // ---- degree-balanced pairing permutation, per 64-row sub-block ----
    // key = (deg << 6) | local64 -> all keys distinct -> valid permutation.
    skey[tid] = (ldeg[tid] << 6) | (tid & 63);
    __syncthreads();
    // odd-even transposition sort, descending, 8 independent 64-sorts
    for (int r = 0; r < 64; ++r) {
        int i = tid & 63;
        int s = tid & ~63;
        if (((i & 1) == (r & 1)) && (i + 1 < 64)) {
            int a = skey[s + i], c = skey[s + i + 1];
            if (a < c) { skey[s + i] = c; skey[s + i + 1] = a; }
        }
        __syncthreads();
    }
    {
        int i = tid & 63;
        int s = tid & ~63;
        // output slot i: group g<32 takes rank g (heavy), its partner slot
        // 32+g takes rank 63-g (light) -> per-group sum ~uniform
        int rank = (i < 32) ? i : (95 - i);
        int loc = skey[s + rank] & 63;
        perm[node0 + s + i] = node0 + s + loc;
    }
}

// ---------------------------------------------------------------- fused GIN layer: gather -> LDS -> MFMA MLP -> write | pool
// BM=64, 512 threads, 16.9 KB LDS, one 32x32 MFMA tile per wave (acc=16 VGPR).
// Gather: R0 control flow (16 lanes/row, 2 sequential rows per group) BUT the
// two rows come from the degree-balanced permutation (heavy rank g paired
// with light rank 63-g) so every group's total edge count is ~uniform and the
// block barrier stops amplifying degree variance. Per-node accumulation order
// (self, then ascending edges, 4-batch + tail) unchanged -> bit-exact.

template <int L, int RELU, int POOL>
__launch_bounds__(512)
__global__ void fused_gin_kernel(const uint4* __restrict__ h4,
                                 const int* __restrict__ offs, const int* __restrict__ csr,
                                 const int* __restrict__ perm,
                                 const unsigned short* __restrict__ w1s, const float* __restrict__ b1,
                                 const unsigned short* __restrict__ w2s, const float* __restrict__ b2,
                                 unsigned short* __restrict__ hout,
                                 const int* __restrict__ batch, float* __restrict__ pooled,
                                 int n) {
    __shared__ __align__(16) unsigned short zs[FBM * PQ2];   // 16.9 KB

    int tid = threadIdx.x;
    int row0 = blockIdx.x * FBM;

    // ---- gather phase: z = h[node] + sum h[src], fp32 accum -> bf16 into LDS
    {
        int gl = tid & 15;
        int grp = tid >> 4;    // 0..31
        int pbase = blockIdx.x << 6;
        int nodeA = perm[pbase + grp];
        int nodeB = perm[pbase + 32 + grp];
        #pragma unroll
        for (int it = 0; it < 2; ++it) {
            int node = it ? nodeB : nodeA;
            int rr = node - row0;
            unsigned o0 = 0, o1 = 0, o2 = 0, o3 = 0;
            if (node < n) {
                int beg = offs[node], end = offs[node + 1];
                f32x2 a[4];
                uint4 self = h4[node * 16 + gl];
                a[0] = bf2(self.x);
                a[1] = bf2(self.y);
                a[2] = bf2(self.z);
                a[3] = bf2(self.w);
                int e = beg;
                for (; e + 4 <= end; e += 4) {
                    int s0 = csr[e], s1 = csr[e + 1], s2 = csr[e + 2], s3 = csr[e + 3];
                    uint4 v0 = h4[s0 * 16 + gl];
                    uint4 v1 = h4[s1 * 16 + gl];
                    uint4 v2 = h4[s2 * 16 + gl];
                    uint4 v3 = h4[s3 * 16 + gl];
                    acc8(a, v0); acc8(a, v1); acc8(a, v2); acc8(a, v3);
                }
                for (; e < end; ++e) {
                    uint4 v = h4[csr[e] * 16 + gl];
                    acc8(a, v);
                }
                o0 = (unsigned)f2bf(a[0][0]) | ((unsigned)f2bf(a[0][1]) << 16);
                o1 = (unsigned)f2bf(a[1][0]) | ((unsigned)f2bf(a[1][1]) << 16);
                o2 = (unsigned)f2bf(a[2][0]) | ((unsigned)f2bf(a[2][1]) << 16);
                o3 = (unsigned)f2bf(a[3][0]) | ((unsigned)f2bf(a[3][1]) << 16);
            }
            *(uint2*)&zs[rr * PQ2 + gl * 8]     = make_uint2(o0, o1);
            *(uint2*)&zs[rr * PQ2 + gl * 8 + 4] = make_uint2(o2, o3);
        }
    }
    __syncthreads();

    int wv = tid >> 6;         // 0..7
    int lane = tid & 63;
    int l31 = lane & 31;
    int kh = lane >> 5;
    int rt = wv & 1;           // 2 row tiles of 32
    int ct = wv >> 1;          // 4 col tiles of 32
    int arow = rt * 32 + l31;

    // ---- matmul 1: t = relu(z @ w1 + b1)
    f32x16 acc;
    {
        float bv = b1[ct * 32 + l31];
        #pragma unroll
        for (int r = 0; r < 16; ++r) acc[r] = bv;
    }
    #pragma unroll
    for (int k0 = 0; k0 < 8; ++k0) {
        short8 afr;
        {
            short4v lo = *(const short4v*)&zs[arow * PQ2 + k0 * 16 + kh * 8];
            short4v hi = *(const short4v*)&zs[arow * PQ2 + k0 * 16 + kh * 8 + 4];
            afr = (short8){lo[0], lo[1], lo[2], lo[3], hi[0], hi[1], hi[2], hi[3]};
        }
        short8 bfr = *(const short8*)&w1s[(((ct * 8 + k0) * 64) + lane) * 8];
        acc = __builtin_amdgcn_mfma_f32_32x32x16_bf16(afr, bfr, acc, 0, 0, 0);
    }
    __syncthreads();

    #pragma unroll
    for (int reg = 0; reg < 16; ++reg) {
        int crow = (reg & 3) + 8 * (reg >> 2) + 4 * kh;
        zs[(rt * 32 + crow) * PQ2 + ct * 32 + l31] = f2bf(fmaxf(acc[reg], 0.f));
    }
    __syncthreads();

    // ---- matmul 2: h = t @ w2 + b2 [+ relu]
    {
        float bv = b2[ct * 32 + l31];
        #pragma unroll
        for (int r = 0; r < 16; ++r) acc[r] = bv;
    }
    #pragma unroll
    for (int k0 = 0; k0 < 8; ++k0) {
        short8 afr;
        {
            short4v lo = *(const short4v*)&zs[arow * PQ2 + k0 * 16 + kh * 8];
            short4v hi = *(const short4v*)&zs[arow * PQ2 + k0 * 16 + kh * 8 + 4];
            afr = (short8){lo[0], lo[1], lo[2], lo[3], hi[0], hi[1], hi[2], hi[3]};
        }
        short8 bfr = *(const short8*)&w2s[(((ct * 8 + k0) * 64) + lane) * 8];
        acc = __builtin_amdgcn_mfma_f32_32x32x16_bf16(afr, bfr, acc, 0, 0, 0);
    }
    __syncthreads();

    #pragma unroll
    for (int reg = 0; reg < 16; ++reg) {
        int crow = (reg & 3) + 8 * (reg >> 2) + 4 * kh;
        float v = acc[reg];
        if (RELU) v = fmaxf(v, 0.f);
        zs[(rt * 32 + crow) * PQ2 + ct * 32 + l31] = f2bf(v);
    }
    __syncthreads();

    if (!POOL) {
        for (int i = tid; i < FBM * 16; i += 512) {
            int r = i >> 4, c = i & 15;
            int row = row0 + r;
            if (row < n) {
                uint2 a2 = *(const uint2*)&zs[r * PQ2 + c * 8];
                uint2 b2v = *(const uint2*)&zs[r * PQ2 + c * 8 + 4];
                ((uint4*)hout)[row * 16 + c] = make_uint4(a2.x, a2.y, b2v.x, b2v.y);
            }
        }
    } else {
        // pool epilogue from LDS tile (batch sorted)
        int c2 = tid & 63;      // uint column (ch 2*c2, 2*c2+1)
        int rs = tid >> 6;      // 0..7
        float a0 = 0.f, a1 = 0.f;
        int prevg = -1;
        #pragma unroll
        for (int i = 0; i < FBM / 8; ++i) {
            int r = rs + 8 * i;
            int row = row0 + r;
            if (row >= n) break;
            int g = batch[row];
            if (g != prevg) {
                if (prevg >= 0) {
                    atomicAdd(&pooled[prevg * CH + 2 * c2], a0);
                    atomicAdd(&pooled[prevg * CH + 2 * c2 + 1], a1);
                }
                prevg = g; a0 = 0.f; a1 = 0.f;
            }
            unsigned v = *(const unsigned*)&zs[r * PQ2 + c2 * 2];
            a0 += bflo(v); a1 += bfhi(v);
        }
        if (prevg >= 0) {
            atomicAdd(&pooled[prevg * CH + 2 * c2], a0);
            atomicAdd(&pooled[prevg * CH + 2 * c2 + 1], a1);
        }
    }
}

// ---------------------------------------------------------------- final linear

__global__ void final_linear_kernel(const float* __restrict__ pooled, const float* __restrict__ lin_w,
                                    const float* __restrict__ lin_b, float* __restrict__ out) {
    int g = blockIdx.x;
    int tid = threadIdx.x;   // 128
    __shared__ float pl[CH];
    pl[tid] = pooled[g * CH + tid];
    __syncthreads();
    if (tid < OUTC) {
        float a = lin_b[tid];
        #pragma unroll 16
        for (int c = 0; c < CH; ++c) a = fmaf(pl[c], lin_w[c * OUTC + tid], a);
        out[g * OUTC + tid] = a;
    }
}

// ---------------------------------------------------------------- launch

static inline size_t aln(size_t x) { return (x + 255) & ~size_t(255); }

extern "C" void kernel_launch(void* const* d_in, const int* in_sizes, int n_in,
                              void* d_out, int out_size, void* d_ws, size_t ws_size,
                              hipStream_t stream) {
    const float* x      = (const float*)d_in[0];
    const int*   ei     = (const int*)d_in[1];
    const int*   batch  = (const int*)d_in[2];
    const float* w1[3]  = {(const float*)d_in[3], (const float*)d_in[7],  (const float*)d_in[11]};
    const float* b1[3]  = {(const float*)d_in[4], (const float*)d_in[8],  (const float*)d_in[12]};
    const float* w2[3]  = {(const float*)d_in[5], (const float*)d_in[9],  (const float*)d_in[13]};
    const float* b2[3]  = {(const float*)d_in[6], (const float*)d_in[10], (const float*)d_in[14]};
    const float* lin_w  = (const float*)d_in[15];
    const float* lin_b  = (const float*)d_in[16];
    float* out = (float*)d_out;

    int E = in_sizes[1] / 2;
    int N = in_sizes[2];
    int n_graphs = out_size / OUTC;
    const int* src = ei;
    const int* dst = ei + E;

    char* p = (char*)d_ws;
    int* bucketCnt  = (int*)p; p += aln(NB * 4);
    unsigned* pairs = (unsigned*)p; p += aln((size_t)NB * BCAP * 4);
    int* offs       = (int*)p; p += aln((size_t)(N + 1) * 4);
    int* csr        = (int*)p; p += aln((size_t)E * 4);
    int* perm       = (int*)p; p += aln((size_t)((N + 511) & ~511) * 4);
    unsigned short* xb = (unsigned short*)p; p += aln((size_t)N * CH * 2);
    unsigned short* hA = (unsigned short*)p; p += aln((size_t)N * CH * 2);
    unsigned short* hB = (unsigned short*)p; p += aln((size_t)N * CH * 2);
    float* pooled = (float*)p; p += aln((size_t)n_graphs * CH * 4);
    unsigned short* wt[6];
    for (int i = 0; i < 6; ++i) { wt[i] = (unsigned short*)p; p += aln((size_t)CH * CH * 2); }
    (void)ws_size; (void)n_in;

    // bucketCnt must be zero before partition blocks run
    hipMemsetAsync(bucketCnt, 0, NB * 4, stream);

    // mega-prep: partition + convert x + swizzle weights + zero pooled
    int n4 = N * CH / 4;
    int nConvBlk = (n4 + 255) / 256;
    int nPartBlk = (E + PCHUNK - 1) / PCHUNK;
    int nPooled4 = n_graphs * CH / 4;
    int nZeroBlk = (nPooled4 + 255) / 256;
    WPtrs wp;
    for (int l = 0; l < 3; ++l) {
        wp.s[2 * l] = w1[l];     wp.d[2 * l] = wt[2 * l];
        wp.s[2 * l + 1] = w2[l]; wp.d[2 * l + 1] = wt[2 * l + 1];
    }
    prep_part_kernel<<<nPartBlk + nConvBlk + 384 + nZeroBlk, 256, 0, stream>>>(
        src, dst, bucketCnt, pairs, E, nPartBlk,
        (const float4*)x, (uint2*)xb, n4, nConvBlk, wp,
        (uint4*)pooled, nPooled4);

    build_csr_kernel<<<NB, 512, 0, stream>>>(pairs, bucketCnt, offs, csr, perm, N);

    int fblk = (N + FBM - 1) / FBM;

    // three fused GIN layers
    fused_gin_kernel<0, 1, 0><<<fblk, 512, 0, stream>>>((const uint4*)xb, offs, csr, perm,
        wt[0], b1[0], wt[1], b2[0], hA, batch, pooled, N);
    fused_gin_kernel<1, 1, 0><<<fblk, 512, 0, stream>>>((const uint4*)hA, offs, csr, perm,
        wt[2], b1[1], wt[3], b2[1], hB, batch, pooled, N);
    fused_gin_kernel<2, 0, 1><<<fblk, 512, 0, stream>>>((const uint4*)hB, offs, csr, perm,
        wt[4], b1[2], wt[5], b2[2], (unsigned short*)nullptr, batch, pooled, N);

    final_linear_kernel<<<n_graphs, CH, 0, stream>>>(pooled, lin_w, lin_b, out);
}

// Round 8
// 383.805 us; speedup vs baseline: 1.3824x; 1.0012x over previous
//
#include <hip/hip_runtime.h>

#define CH 128
#define OUTC 10
#define NB 256            // buckets (dst >> 9), only ceil(N/512) used
#define BCAP 10240        // per-bucket pair capacity (avg ~8192, >22 sigma margin)
#define PCHUNK 2048       // edges per partition block
#define PQ2 132           // LDS pitch in bf16 (dword stride 66 -> 2-way bank alias = free)
#define FBM 64            // rows per fused-layer block

typedef __attribute__((ext_vector_type(8))) short short8;
typedef __attribute__((ext_vector_type(4))) short short4v;
typedef __attribute__((ext_vector_type(16))) float f32x16;
typedef __attribute__((ext_vector_type(2))) float f32x2;

// ---------------------------------------------------------------- helpers

__device__ inline unsigned short f2bf(float f) {
    unsigned u = __builtin_bit_cast(unsigned, f);
    u += 0x7fffu + ((u >> 16) & 1u);   // RNE
    return (unsigned short)(u >> 16);
}
__device__ inline float bflo(unsigned u) { return __builtin_bit_cast(float, u << 16); }
__device__ inline float bfhi(unsigned u) { return __builtin_bit_cast(float, u & 0xffff0000u); }

// packed bf16 pair -> f32x2 (lshl / and, then one packed add on the consumer)
__device__ inline f32x2 bf2(unsigned u) {
    return (f32x2){__builtin_bit_cast(float, u << 16),
                   __builtin_bit_cast(float, u & 0xffff0000u)};
}

__device__ inline void acc8(f32x2* a, const uint4& v) {
    a[0] += bf2(v.x);
    a[1] += bf2(v.y);
    a[2] += bf2(v.z);
    a[3] += bf2(v.w);
}

// ---------------------------------------------------------------- mega prep: edge partition + x->bf16 + w-swizzle + pooled zero

struct WPtrs { const float* s[6]; unsigned short* d[6]; };

__global__ void prep_part_kernel(const int* __restrict__ src, const int* __restrict__ dst,
                                 int* __restrict__ bucketCnt, unsigned* __restrict__ pairs, int E,
                                 int nPartBlk,
                                 const float4* __restrict__ x4, uint2* __restrict__ xb, int n4,
                                 int nConvBlk, WPtrs p,
                                 uint4* __restrict__ pooled4, int nPooled4) {
    __shared__ int hist[NB];
    __shared__ int base[NB];
    __shared__ int cur[NB];
    int tid = threadIdx.x;   // 256
    int b = blockIdx.x;

    if (b < nPartBlk) {
        int e0 = b * PCHUNK;
        hist[tid] = 0;
        __syncthreads();
        #pragma unroll
        for (int i = 0; i < PCHUNK / 256; ++i) {
            int e = e0 + tid + i * 256;
            if (e < E) atomicAdd(&hist[dst[e] >> 9], 1);
        }
        __syncthreads();
        {
            int c = hist[tid];
            base[tid] = (c > 0) ? atomicAdd(&bucketCnt[tid], c) : 0;
            cur[tid] = 0;
        }
        __syncthreads();
        #pragma unroll
        for (int i = 0; i < PCHUNK / 256; ++i) {
            int e = e0 + tid + i * 256;
            if (e < E) {
                int d = dst[e];
                int bkt = d >> 9;
                int pos = base[bkt] + atomicAdd(&cur[bkt], 1);
                if (pos < BCAP)
                    pairs[bkt * BCAP + pos] = ((unsigned)(d & 511) << 17) | (unsigned)src[e];
            }
        }
    } else if (b < nPartBlk + nConvBlk) {
        int i = (b - nPartBlk) * 256 + tid;
        if (i < n4) {
            float4 v = x4[i];
            uint2 o;
            o.x = (unsigned)f2bf(v.x) | ((unsigned)f2bf(v.y) << 16);
            o.y = (unsigned)f2bf(v.z) | ((unsigned)f2bf(v.w) << 16);
            xb[i] = o;
        }
    } else if (b < nPartBlk + nConvBlk + 384) {
        int bb = b - nPartBlk - nConvBlk;  // 0..383
        int m = bb >> 6;                   // matrix 0..5
        int i = (bb & 63) * 256 + tid;     // 0..16383
        int j = i & 7;
        int l = (i >> 3) & 63;
        int k0 = (i >> 9) & 7;
        int ct = (i >> 12) & 3;
        int k = k0 * 16 + ((l >> 5) << 3) + j;
        int nn = ct * 32 + (l & 31);
        p.d[m][i] = f2bf(p.s[m][k * CH + nn]);
    } else {
        int i = (b - nPartBlk - nConvBlk - 384) * 256 + tid;
        if (i < nPooled4) pooled4[i] = make_uint4(0, 0, 0, 0);
    }
}

// ---------------------------------------------------------------- CSR build (self-scans bucket counts)

__launch_bounds__(512)
__global__ void build_csr_kernel(const unsigned* __restrict__ pairs, const int* __restrict__ bucketCnt,
                                 int* __restrict__ offs, int* __restrict__ csr, int N) {
    __shared__ int bsm[NB];
    __shared__ int ldeg[512];
    __shared__ int s0[512], s1[512];
    __shared__ int lexc[512];
    __shared__ int lcur[512];
    __shared__ int lcsr[BCAP];

    int b = blockIdx.x;
    int node0 = b << 9;
    if (node0 >= N) return;
    int nLocal = min(512, N - node0);
    int tid = threadIdx.x;   // 512

    if (tid < NB) bsm[tid] = bucketCnt[tid];
    __syncthreads();
    for (int off = 1; off < NB; off <<= 1) {
        int t = 0;
        if (tid < NB) t = (tid >= off) ? bsm[tid - off] : 0;
        __syncthreads();
        if (tid < NB) bsm[tid] += t;
        __syncthreads();
    }
    int cnt = min(bucketCnt[b], BCAP);
    int gbase = bsm[b] - bucketCnt[b];

    ldeg[tid] = 0;
    __syncthreads();
    for (int i = tid; i < cnt; i += 512)
        atomicAdd(&ldeg[pairs[b * BCAP + i] >> 17], 1);
    __syncthreads();

    s0[tid] = ldeg[tid];
    __syncthreads();
    int* sp = s0; int* dp = s1;
    for (int off = 1; off < 512; off <<= 1) {
        dp[tid] = sp[tid] + ((tid >= off) ? sp[tid - off] : 0);
        __syncthreads();
        int* t = sp; sp = dp; dp = t;
    }
    {
        int ex = sp[tid] - ldeg[tid];
        lexc[tid] = ex;
        lcur[tid] = ex;
    }
    __syncthreads();

    for (int i = tid; i < cnt; i += 512) {
        unsigned w = pairs[b * BCAP + i];
        int ppos = atomicAdd(&lcur[w >> 17], 1);
        lcsr[ppos] = (int)(w & 0x1ffffu);
    }
    __syncthreads();

    for (int i = tid; i < cnt; i += 512) csr[gbase + i] = lcsr[i];
    for (int i = tid; i < nLocal; i += 512) offs[node0 + i] = gbase + lexc[i];
    if (tid == 0 && node0 + nLocal == N) offs[N] = gbase + cnt;
}

// ---------------------------------------------------------------- fused GIN layer: gather -> LDS -> MFMA MLP -> write | pool
// R8: 256-thread blocks (4 waves), FBM=64. 1563 blocks now ALL fit in the
// chip's 2048 block slots (32 waves/CU / 4 waves per block x 256 CU) ->
// single scheduling round, no 53%-full second round (the ~24% concurrency
// loss that capped every 512-thread variant at ~2.7 TB/s; R6's tail-free
// split gather hit 3.63 on the same data). Gather: 8 lanes/row (2x uint4
// per edge -> 8 loads in flight/wave), R0's two-sequential-rows loop, no
// predication (R2), no sched pins (R4). MFMA: 4 waves x two 32x32 col-tiles
// each, A-frag shared. Per-channel accumulation order (self, then ascending
// edges, 4-batch + tail) unchanged -> bit-exact.

template <int L, int RELU, int POOL>
__launch_bounds__(256)
__global__ void fused_gin_kernel(const uint4* __restrict__ h4,
                                 const int* __restrict__ offs, const int* __restrict__ csr,
                                 const unsigned short* __restrict__ w1s, const float* __restrict__ b1,
                                 const unsigned short* __restrict__ w2s, const float* __restrict__ b2,
                                 unsigned short* __restrict__ hout,
                                 const int* __restrict__ batch, float* __restrict__ pooled,
                                 int n) {
    __shared__ __align__(16) unsigned short zs[FBM * PQ2];   // 16.9 KB

    int tid = threadIdx.x;
    int row0 = blockIdx.x * FBM;

    // ---- gather phase: z = h[node] + sum h[src], fp32 accum -> bf16 into LDS
    {
        int gl = tid & 7;          // 8 lanes/row, 32B (16ch) per lane
        int grp = tid >> 3;        // 0..31
        int g2 = gl * 2;           // uint4 index within the 16-uint4 row
        #pragma unroll
        for (int it = 0; it < 2; ++it) {
            int rr = grp + 32 * it;
            int node = row0 + rr;
            unsigned o0 = 0, o1 = 0, o2 = 0, o3 = 0, o4 = 0, o5 = 0, o6 = 0, o7 = 0;
            if (node < n) {
                int beg = offs[node], end = offs[node + 1];
                f32x2 a[8];
                {
                    uint4 sa = h4[node * 16 + g2];
                    uint4 sb = h4[node * 16 + g2 + 1];
                    a[0] = bf2(sa.x); a[1] = bf2(sa.y); a[2] = bf2(sa.z); a[3] = bf2(sa.w);
                    a[4] = bf2(sb.x); a[5] = bf2(sb.y); a[6] = bf2(sb.z); a[7] = bf2(sb.w);
                }
                int e = beg;
                for (; e + 4 <= end; e += 4) {
                    int s0 = csr[e], s1 = csr[e + 1], s2 = csr[e + 2], s3 = csr[e + 3];
                    uint4 v0a = h4[s0 * 16 + g2], v0b = h4[s0 * 16 + g2 + 1];
                    uint4 v1a = h4[s1 * 16 + g2], v1b = h4[s1 * 16 + g2 + 1];
                    uint4 v2a = h4[s2 * 16 + g2], v2b = h4[s2 * 16 + g2 + 1];
                    uint4 v3a = h4[s3 * 16 + g2], v3b = h4[s3 * 16 + g2 + 1];
                    acc8(a, v0a); acc8(a + 4, v0b);
                    acc8(a, v1a); acc8(a + 4, v1b);
                    acc8(a, v2a); acc8(a + 4, v2b);
                    acc8(a, v3a); acc8(a + 4, v3b);
                }
                for (; e < end; ++e) {
                    int s0 = csr[e];
                    uint4 va = h4[s0 * 16 + g2], vb = h4[s0 * 16 + g2 + 1];
                    acc8(a, va); acc8(a + 4, vb);
                }
                o0 = (unsigned)f2bf(a[0][0]) | ((unsigned)f2bf(a[0][1]) << 16);
                o1 = (unsigned)f2bf(a[1][0]) | ((unsigned)f2bf(a[1][1]) << 16);
                o2 = (unsigned)f2bf(a[2][0]) | ((unsigned)f2bf(a[2][1]) << 16);
                o3 = (unsigned)f2bf(a[3][0]) | ((unsigned)f2bf(a[3][1]) << 16);
                o4 = (unsigned)f2bf(a[4][0]) | ((unsigned)f2bf(a[4][1]) << 16);
                o5 = (unsigned)f2bf(a[5][0]) | ((unsigned)f2bf(a[5][1]) << 16);
                o6 = (unsigned)f2bf(a[6][0]) | ((unsigned)f2bf(a[6][1]) << 16);
                o7 = (unsigned)f2bf(a[7][0]) | ((unsigned)f2bf(a[7][1]) << 16);
            }
            *(uint2*)&zs[rr * PQ2 + gl * 16]      = make_uint2(o0, o1);
            *(uint2*)&zs[rr * PQ2 + gl * 16 + 4]  = make_uint2(o2, o3);
            *(uint2*)&zs[rr * PQ2 + gl * 16 + 8]  = make_uint2(o4, o5);
            *(uint2*)&zs[rr * PQ2 + gl * 16 + 12] = make_uint2(o6, o7);
        }
    }
    __syncthreads();

    int wv = tid >> 6;         // 0..3
    int lane = tid & 63;
    int l31 = lane & 31;
    int kh = lane >> 5;
    int rt = wv & 1;           // 2 row tiles of 32
    int cp = wv >> 1;          // 0..1 -> col tiles {2cp, 2cp+1}
    int arow = rt * 32 + l31;
    int ct0 = cp * 2, ct1 = cp * 2 + 1;

    // ---- matmul 1: t = relu(z @ w1 + b1), two col tiles per wave
    f32x16 acc0, acc1;
    {
        float bv0 = b1[ct0 * 32 + l31];
        float bv1 = b1[ct1 * 32 + l31];
        #pragma unroll
        for (int r = 0; r < 16; ++r) { acc0[r] = bv0; acc1[r] = bv1; }
    }
    #pragma unroll
    for (int k0 = 0; k0 < 8; ++k0) {
        short8 afr;
        {
            short4v lo = *(const short4v*)&zs[arow * PQ2 + k0 * 16 + kh * 8];
            short4v hi = *(const short4v*)&zs[arow * PQ2 + k0 * 16 + kh * 8 + 4];
            afr = (short8){lo[0], lo[1], lo[2], lo[3], hi[0], hi[1], hi[2], hi[3]};
        }
        short8 bfr0 = *(const short8*)&w1s[(((ct0 * 8 + k0) * 64) + lane) * 8];
        short8 bfr1 = *(const short8*)&w1s[(((ct1 * 8 + k0) * 64) + lane) * 8];
        acc0 = __builtin_amdgcn_mfma_f32_32x32x16_bf16(afr, bfr0, acc0, 0, 0, 0);
        acc1 = __builtin_amdgcn_mfma_f32_32x32x16_bf16(afr, bfr1, acc1, 0, 0, 0);
    }
    __syncthreads();

    #pragma unroll
    for (int reg = 0; reg < 16; ++reg) {
        int crow = (reg & 3) + 8 * (reg >> 2) + 4 * kh;
        zs[(rt * 32 + crow) * PQ2 + ct0 * 32 + l31] = f2bf(fmaxf(acc0[reg], 0.f));
        zs[(rt * 32 + crow) * PQ2 + ct1 * 32 + l31] = f2bf(fmaxf(acc1[reg], 0.f));
    }
    __syncthreads();

    // ---- matmul 2: h = t @ w2 + b2 [+ relu]
    {
        float bv0 = b2[ct0 * 32 + l31];
        float bv1 = b2[ct1 * 32 + l31];
        #pragma unroll
        for (int r = 0; r < 16; ++r) { acc0[r] = bv0; acc1[r] = bv1; }
    }
    #pragma unroll
    for (int k0 = 0; k0 < 8; ++k0) {
        short8 afr;
        {
            short4v lo = *(const short4v*)&zs[arow * PQ2 + k0 * 16 + kh * 8];
            short4v hi = *(const short4v*)&zs[arow * PQ2 + k0 * 16 + kh * 8 + 4];
            afr = (short8){lo[0], lo[1], lo[2], lo[3], hi[0], hi[1], hi[2], hi[3]};
        }
        short8 bfr0 = *(const short8*)&w2s[(((ct0 * 8 + k0) * 64) + lane) * 8];
        short8 bfr1 = *(const short8*)&w2s[(((ct1 * 8 + k0) * 64) + lane) * 8];
        acc0 = __builtin_amdgcn_mfma_f32_32x32x16_bf16(afr, bfr0, acc0, 0, 0, 0);
        acc1 = __builtin_amdgcn_mfma_f32_32x32x16_bf16(afr, bfr1, acc1, 0, 0, 0);
    }
    __syncthreads();

    #pragma unroll
    for (int reg = 0; reg < 16; ++reg) {
        int crow = (reg & 3) + 8 * (reg >> 2) + 4 * kh;
        float v0 = acc0[reg];
        float v1 = acc1[reg];
        if (RELU) { v0 = fmaxf(v0, 0.f); v1 = fmaxf(v1, 0.f); }
        zs[(rt * 32 + crow) * PQ2 + ct0 * 32 + l31] = f2bf(v0);
        zs[(rt * 32 + crow) * PQ2 + ct1 * 32 + l31] = f2bf(v1);
    }
    __syncthreads();

    if (!POOL) {
        for (int i = tid; i < FBM * 16; i += 256) {
            int r = i >> 4, c = i & 15;
            int row = row0 + r;
            if (row < n) {
                uint2 a2 = *(const uint2*)&zs[r * PQ2 + c * 8];
                uint2 b2v = *(const uint2*)&zs[r * PQ2 + c * 8 + 4];
                ((uint4*)hout)[row * 16 + c] = make_uint4(a2.x, a2.y, b2v.x, b2v.y);
            }
        }
    } else {
        // pool epilogue from LDS tile (batch sorted)
        int c2 = tid & 63;      // uint column (ch 2*c2, 2*c2+1)
        int rs = tid >> 6;      // 0..3
        float a0 = 0.f, a1 = 0.f;
        int prevg = -1;
        #pragma unroll
        for (int i = 0; i < FBM / 4; ++i) {
            int r = rs + 4 * i;
            int row = row0 + r;
            if (row >= n) break;
            int g = batch[row];
            if (g != prevg) {
                if (prevg >= 0) {
                    atomicAdd(&pooled[prevg * CH + 2 * c2], a0);
                    atomicAdd(&pooled[prevg * CH + 2 * c2 + 1], a1);
                }
                prevg = g; a0 = 0.f; a1 = 0.f;
            }
            unsigned v = *(const unsigned*)&zs[r * PQ2 + c2 * 2];
            a0 += bflo(v); a1 += bfhi(v);
        }
        if (prevg >= 0) {
            atomicAdd(&pooled[prevg * CH + 2 * c2], a0);
            atomicAdd(&pooled[prevg * CH + 2 * c2 + 1], a1);
        }
    }
}

// ---------------------------------------------------------------- final linear

__global__ void final_linear_kernel(const float* __restrict__ pooled, const float* __restrict__ lin_w,
                                    const float* __restrict__ lin_b, float* __restrict__ out) {
    int g = blockIdx.x;
    int tid = threadIdx.x;   // 128
    __shared__ float pl[CH];
    pl[tid] = pooled[g * CH + tid];
    __syncthreads();
    if (tid < OUTC) {
        float a = lin_b[tid];
        #pragma unroll 16
        for (int c = 0; c < CH; ++c) a = fmaf(pl[c], lin_w[c * OUTC + tid], a);
        out[g * OUTC + tid] = a;
    }
}

// ---------------------------------------------------------------- launch

static inline size_t aln(size_t x) { return (x + 255) & ~size_t(255); }

extern "C" void kernel_launch(void* const* d_in, const int* in_sizes, int n_in,
                              void* d_out, int out_size, void* d_ws, size_t ws_size,
                              hipStream_t stream) {
    const float* x      = (const float*)d_in[0];
    const int*   ei     = (const int*)d_in[1];
    const int*   batch  = (const int*)d_in[2];
    const float* w1[3]  = {(const float*)d_in[3], (const float*)d_in[7],  (const float*)d_in[11]};
    const float* b1[3]  = {(const float*)d_in[4], (const float*)d_in[8],  (const float*)d_in[12]};
    const float* w2[3]  = {(const float*)d_in[5], (const float*)d_in[9],  (const float*)d_in[13]};
    const float* b2[3]  = {(const float*)d_in[6], (const float*)d_in[10], (const float*)d_in[14]};
    const float* lin_w  = (const float*)d_in[15];
    const float* lin_b  = (const float*)d_in[16];
    float* out = (float*)d_out;

    int E = in_sizes[1] / 2;
    int N = in_sizes[2];
    int n_graphs = out_size / OUTC;
    const int* src = ei;
    const int* dst = ei + E;

    char* p = (char*)d_ws;
    int* bucketCnt  = (int*)p; p += aln(NB * 4);
    unsigned* pairs = (unsigned*)p; p += aln((size_t)NB * BCAP * 4);
    int* offs       = (int*)p; p += aln((size_t)(N + 1) * 4);
    int* csr        = (int*)p; p += aln((size_t)E * 4);
    unsigned short* xb = (unsigned short*)p; p += aln((size_t)N * CH * 2);
    unsigned short* hA = (unsigned short*)p; p += aln((size_t)N * CH * 2);
    unsigned short* hB = (unsigned short*)p; p += aln((size_t)N * CH * 2);
    float* pooled = (float*)p; p += aln((size_t)n_graphs * CH * 4);
    unsigned short* wt[6];
    for (int i = 0; i < 6; ++i) { wt[i] = (unsigned short*)p; p += aln((size_t)CH * CH * 2); }
    (void)ws_size; (void)n_in;

    // bucketCnt must be zero before partition blocks run
    hipMemsetAsync(bucketCnt, 0, NB * 4, stream);

    // mega-prep: partition + convert x + swizzle weights + zero pooled
    int n4 = N * CH / 4;
    int nConvBlk = (n4 + 255) / 256;
    int nPartBlk = (E + PCHUNK - 1) / PCHUNK;
    int nPooled4 = n_graphs * CH / 4;
    int nZeroBlk = (nPooled4 + 255) / 256;
    WPtrs wp;
    for (int l = 0; l < 3; ++l) {
        wp.s[2 * l] = w1[l];     wp.d[2 * l] = wt[2 * l];
        wp.s[2 * l + 1] = w2[l]; wp.d[2 * l + 1] = wt[2 * l + 1];
    }
    prep_part_kernel<<<nPartBlk + nConvBlk + 384 + nZeroBlk, 256, 0, stream>>>(
        src, dst, bucketCnt, pairs, E, nPartBlk,
        (const float4*)x, (uint2*)xb, n4, nConvBlk, wp,
        (uint4*)pooled, nPooled4);

    build_csr_kernel<<<NB, 512, 0, stream>>>(pairs, bucketCnt, offs, csr, N);

    int fblk = (N + FBM - 1) / FBM;

    // three fused GIN layers (256-thread blocks: all 1563 blocks co-resident)
    fused_gin_kernel<0, 1, 0><<<fblk, 256, 0, stream>>>((const uint4*)xb, offs, csr,
        wt[0], b1[0], wt[1], b2[0], hA, batch, pooled, N);
    fused_gin_kernel<1, 1, 0><<<fblk, 256, 0, stream>>>((const uint4*)hA, offs, csr,
        wt[2], b1[1], wt[3], b2[1], hB, batch, pooled, N);
    fused_gin_kernel<2, 0, 1><<<fblk, 256, 0, stream>>>((const uint4*)hB, offs, csr,
        wt[4], b1[2], wt[5], b2[2], (unsigned short*)nullptr, batch, pooled, N);

    final_linear_kernel<<<n_graphs, CH, 0, stream>>>(pooled, lin_w, lin_b, out);
}

// Round 9
// 377.071 us; speedup vs baseline: 1.4071x; 1.0179x over previous
//
#include <hip/hip_runtime.h>

#define CH 128
#define OUTC 10
#define NB2 512           // buckets (dst >> 8): 256-node buckets, 2x csr-build parallelism
#define BSHIFT 8
#define BCAP2 5120        // per-bucket pair capacity (avg ~4096, +16 sigma margin)
#define PCHUNK 2048       // edges per partition block
#define PQ2 132           // LDS pitch in bf16 (dword stride 66 -> 2-way bank alias = free)
#define FBM 64            // rows per fused-layer block

typedef __attribute__((ext_vector_type(8))) short short8;
typedef __attribute__((ext_vector_type(4))) short short4v;
typedef __attribute__((ext_vector_type(16))) float f32x16;
typedef __attribute__((ext_vector_type(2))) float f32x2;

// ---------------------------------------------------------------- helpers

__device__ inline unsigned short f2bf(float f) {
    unsigned u = __builtin_bit_cast(unsigned, f);
    u += 0x7fffu + ((u >> 16) & 1u);   // RNE
    return (unsigned short)(u >> 16);
}
__device__ inline float bflo(unsigned u) { return __builtin_bit_cast(float, u << 16); }
__device__ inline float bfhi(unsigned u) { return __builtin_bit_cast(float, u & 0xffff0000u); }

// packed bf16 pair -> f32x2 (lshl / and, then one packed add on the consumer)
__device__ inline f32x2 bf2(unsigned u) {
    return (f32x2){__builtin_bit_cast(float, u << 16),
                   __builtin_bit_cast(float, u & 0xffff0000u)};
}

__device__ inline void acc8(f32x2* a, const uint4& v) {
    a[0] += bf2(v.x);
    a[1] += bf2(v.y);
    a[2] += bf2(v.z);
    a[3] += bf2(v.w);
}

// ---------------------------------------------------------------- mega prep: edge partition + x->bf16 + w-swizzle + pooled zero

struct WPtrs { const float* s[6]; unsigned short* d[6]; };

__global__ void prep_part_kernel(const int* __restrict__ src, const int* __restrict__ dst,
                                 int* __restrict__ bucketCnt, unsigned* __restrict__ pairs, int E,
                                 int nPartBlk,
                                 const float4* __restrict__ x4, uint2* __restrict__ xb, int n4,
                                 int nConvBlk, WPtrs p,
                                 uint4* __restrict__ pooled4, int nPooled4) {
    __shared__ int hist[NB2];
    __shared__ int base[NB2];
    __shared__ int cur[NB2];
    int tid = threadIdx.x;   // 256
    int b = blockIdx.x;

    if (b < nPartBlk) {
        int e0 = b * PCHUNK;
        hist[tid] = 0; hist[tid + 256] = 0;
        __syncthreads();
        #pragma unroll
        for (int i = 0; i < PCHUNK / 256; ++i) {
            int e = e0 + tid + i * 256;
            if (e < E) atomicAdd(&hist[dst[e] >> BSHIFT], 1);
        }
        __syncthreads();
        #pragma unroll
        for (int k = 0; k < 2; ++k) {
            int t2 = tid + k * 256;
            int c = hist[t2];
            base[t2] = (c > 0) ? atomicAdd(&bucketCnt[t2], c) : 0;
            cur[t2] = 0;
        }
        __syncthreads();
        #pragma unroll
        for (int i = 0; i < PCHUNK / 256; ++i) {
            int e = e0 + tid + i * 256;
            if (e < E) {
                int d = dst[e];
                int bkt = d >> BSHIFT;
                int pos = base[bkt] + atomicAdd(&cur[bkt], 1);
                if (pos < BCAP2)
                    pairs[bkt * BCAP2 + pos] = ((unsigned)(d & 255) << 17) | (unsigned)src[e];
            }
        }
    } else if (b < nPartBlk + nConvBlk) {
        int i = (b - nPartBlk) * 256 + tid;
        if (i < n4) {
            float4 v = x4[i];
            uint2 o;
            o.x = (unsigned)f2bf(v.x) | ((unsigned)f2bf(v.y) << 16);
            o.y = (unsigned)f2bf(v.z) | ((unsigned)f2bf(v.w) << 16);
            xb[i] = o;
        }
    } else if (b < nPartBlk + nConvBlk + 384) {
        int bb = b - nPartBlk - nConvBlk;  // 0..383
        int m = bb >> 6;                   // matrix 0..5
        int i = (bb & 63) * 256 + tid;     // 0..16383
        int j = i & 7;
        int l = (i >> 3) & 63;
        int k0 = (i >> 9) & 7;
        int ct = (i >> 12) & 3;
        int k = k0 * 16 + ((l >> 5) << 3) + j;
        int nn = ct * 32 + (l & 31);
        p.d[m][i] = f2bf(p.s[m][k * CH + nn]);
    } else {
        int i = (b - nPartBlk - nConvBlk - 384) * 256 + tid;
        if (i < nPooled4) pooled4[i] = make_uint4(0, 0, 0, 0);
    }
}

// ---------------------------------------------------------------- CSR build (self-scans bucket counts)
// R9: 256-node buckets (512 of them) -> 392 active blocks (1.5/CU, was 0.77)
// and HALF the per-block serial work (histogram/scatter/copy over ~4096 pairs
// instead of ~8192; degree scan over 256 entries instead of 512). This kernel
// is latency-bound on a single block's barrier-chain -> halving the chain
// should halve its duration. CSR content and per-node order unchanged.

__launch_bounds__(512)
__global__ void build_csr_kernel(const unsigned* __restrict__ pairs, const int* __restrict__ bucketCnt,
                                 int* __restrict__ offs, int* __restrict__ csr, int N) {
    __shared__ int bsm[NB2];
    __shared__ int ldeg[256];
    __shared__ int s0[256], s1[256];
    __shared__ int lexc[256];
    __shared__ int lcur[256];
    __shared__ int lcsr[BCAP2];

    int b = blockIdx.x;
    int node0 = b << BSHIFT;
    if (node0 >= N) return;
    int nLocal = min(256, N - node0);
    int tid = threadIdx.x;   // 512

    bsm[tid] = bucketCnt[tid];
    __syncthreads();
    for (int off = 1; off < NB2; off <<= 1) {
        int t = (tid >= off) ? bsm[tid - off] : 0;
        __syncthreads();
        bsm[tid] += t;
        __syncthreads();
    }
    int cnt = min(bucketCnt[b], BCAP2);
    int gbase = bsm[b] - bucketCnt[b];

    if (tid < 256) ldeg[tid] = 0;
    __syncthreads();
    for (int i = tid; i < cnt; i += 512)
        atomicAdd(&ldeg[pairs[b * BCAP2 + i] >> 17], 1);
    __syncthreads();

    if (tid < 256) s0[tid] = ldeg[tid];
    __syncthreads();
    int* sp = s0; int* dp = s1;
    for (int off = 1; off < 256; off <<= 1) {
        if (tid < 256) dp[tid] = sp[tid] + ((tid >= off) ? sp[tid - off] : 0);
        __syncthreads();
        int* t = sp; sp = dp; dp = t;
    }
    if (tid < 256) {
        int ex = sp[tid] - ldeg[tid];
        lexc[tid] = ex;
        lcur[tid] = ex;
    }
    __syncthreads();

    for (int i = tid; i < cnt; i += 512) {
        unsigned w = pairs[b * BCAP2 + i];
        int ppos = atomicAdd(&lcur[w >> 17], 1);
        lcsr[ppos] = (int)(w & 0x1ffffu);
    }
    __syncthreads();

    for (int i = tid; i < cnt; i += 512) csr[gbase + i] = lcsr[i];
    for (int i = tid; i < nLocal; i += 512) offs[node0 + i] = gbase + lexc[i];
    if (tid == 0 && node0 + nLocal == N) offs[N] = gbase + cnt;
}

// ---------------------------------------------------------------- fused GIN layer: gather -> LDS -> MFMA MLP -> write | pool
// Best-measured configuration (R3: 76.3 us min, VGPR 28, occ ~66%).
// Gather at the empirical per-XCD L2-fill wall (~1 line/cy/XCD, 2.5-2.7 TB/s
// raw) — insensitive to occupancy 32-74%, depth 4-8, block 256/512 (R0-R8).

template <int L, int RELU, int POOL>
__launch_bounds__(512)
__global__ void fused_gin_kernel(const uint4* __restrict__ h4,
                                 const int* __restrict__ offs, const int* __restrict__ csr,
                                 const unsigned short* __restrict__ w1s, const float* __restrict__ b1,
                                 const unsigned short* __restrict__ w2s, const float* __restrict__ b2,
                                 unsigned short* __restrict__ hout,
                                 const int* __restrict__ batch, float* __restrict__ pooled,
                                 int n) {
    __shared__ __align__(16) unsigned short zs[FBM * PQ2];   // 16.9 KB

    int tid = threadIdx.x;
    int row0 = blockIdx.x * FBM;

    // ---- gather phase: z = h[node] + sum h[src], fp32 accum -> bf16 into LDS
    {
        int gl = tid & 15;
        int grp = tid >> 4;    // 0..31
        #pragma unroll
        for (int it = 0; it < 2; ++it) {
            int rr = grp + 32 * it;
            int node = row0 + rr;
            unsigned o0 = 0, o1 = 0, o2 = 0, o3 = 0;
            if (node < n) {
                int beg = offs[node], end = offs[node + 1];
                f32x2 a[4];
                uint4 self = h4[node * 16 + gl];
                a[0] = bf2(self.x);
                a[1] = bf2(self.y);
                a[2] = bf2(self.z);
                a[3] = bf2(self.w);
                int e = beg;
                int elim = beg + ((end - beg) & ~3);   // end of full batches
                if (e < elim) {
                    int s0 = csr[e], s1 = csr[e + 1], s2 = csr[e + 2], s3 = csr[e + 3];
                    for (; e + 8 <= elim; e += 4) {
                        uint4 v0 = h4[s0 * 16 + gl];
                        uint4 v1 = h4[s1 * 16 + gl];
                        uint4 v2 = h4[s2 * 16 + gl];
                        uint4 v3 = h4[s3 * 16 + gl];
                        int t0 = csr[e + 4], t1 = csr[e + 5], t2 = csr[e + 6], t3 = csr[e + 7];
                        acc8(a, v0); acc8(a, v1); acc8(a, v2); acc8(a, v3);
                        s0 = t0; s1 = t1; s2 = t2; s3 = t3;
                    }
                    {
                        uint4 v0 = h4[s0 * 16 + gl];
                        uint4 v1 = h4[s1 * 16 + gl];
                        uint4 v2 = h4[s2 * 16 + gl];
                        uint4 v3 = h4[s3 * 16 + gl];
                        acc8(a, v0); acc8(a, v1); acc8(a, v2); acc8(a, v3);
                        e += 4;
                    }
                }
                for (; e < end; ++e) {
                    uint4 v = h4[csr[e] * 16 + gl];
                    acc8(a, v);
                }
                o0 = (unsigned)f2bf(a[0][0]) | ((unsigned)f2bf(a[0][1]) << 16);
                o1 = (unsigned)f2bf(a[1][0]) | ((unsigned)f2bf(a[1][1]) << 16);
                o2 = (unsigned)f2bf(a[2][0]) | ((unsigned)f2bf(a[2][1]) << 16);
                o3 = (unsigned)f2bf(a[3][0]) | ((unsigned)f2bf(a[3][1]) << 16);
            }
            *(uint2*)&zs[rr * PQ2 + gl * 8]     = make_uint2(o0, o1);
            *(uint2*)&zs[rr * PQ2 + gl * 8 + 4] = make_uint2(o2, o3);
        }
    }
    __syncthreads();

    int wv = tid >> 6;         // 0..7
    int lane = tid & 63;
    int l31 = lane & 31;
    int kh = lane >> 5;
    int rt = wv & 1;           // 2 row tiles of 32
    int ct = wv >> 1;          // 4 col tiles of 32
    int arow = rt * 32 + l31;

    // ---- matmul 1: t = relu(z @ w1 + b1)
    f32x16 acc;
    {
        float bv = b1[ct * 32 + l31];
        #pragma unroll
        for (int r = 0; r < 16; ++r) acc[r] = bv;
    }
    #pragma unroll
    for (int k0 = 0; k0 < 8; ++k0) {
        short8 afr;
        {
            short4v lo = *(const short4v*)&zs[arow * PQ2 + k0 * 16 + kh * 8];
            short4v hi = *(const short4v*)&zs[arow * PQ2 + k0 * 16 + kh * 8 + 4];
            afr = (short8){lo[0], lo[1], lo[2], lo[3], hi[0], hi[1], hi[2], hi[3]};
        }
        short8 bfr = *(const short8*)&w1s[(((ct * 8 + k0) * 64) + lane) * 8];
        acc = __builtin_amdgcn_mfma_f32_32x32x16_bf16(afr, bfr, acc, 0, 0, 0);
    }
    __syncthreads();

    #pragma unroll
    for (int reg = 0; reg < 16; ++reg) {
        int crow = (reg & 3) + 8 * (reg >> 2) + 4 * kh;
        zs[(rt * 32 + crow) * PQ2 + ct * 32 + l31] = f2bf(fmaxf(acc[reg], 0.f));
    }
    __syncthreads();

    // ---- matmul 2: h = t @ w2 + b2 [+ relu]
    {
        float bv = b2[ct * 32 + l31];
        #pragma unroll
        for (int r = 0; r < 16; ++r) acc[r] = bv;
    }
    #pragma unroll
    for (int k0 = 0; k0 < 8; ++k0) {
        short8 afr;
        {
            short4v lo = *(const short4v*)&zs[arow * PQ2 + k0 * 16 + kh * 8];
            short4v hi = *(const short4v*)&zs[arow * PQ2 + k0 * 16 + kh * 8 + 4];
            afr = (short8){lo[0], lo[1], lo[2], lo[3], hi[0], hi[1], hi[2], hi[3]};
        }
        short8 bfr = *(const short8*)&w2s[(((ct * 8 + k0) * 64) + lane) * 8];
        acc = __builtin_amdgcn_mfma_f32_32x32x16_bf16(afr, bfr, acc, 0, 0, 0);
    }
    __syncthreads();

    #pragma unroll
    for (int reg = 0; reg < 16; ++reg) {
        int crow = (reg & 3) + 8 * (reg >> 2) + 4 * kh;
        float v = acc[reg];
        if (RELU) v = fmaxf(v, 0.f);
        zs[(rt * 32 + crow) * PQ2 + ct * 32 + l31] = f2bf(v);
    }
    __syncthreads();

    if (!POOL) {
        for (int i = tid; i < FBM * 16; i += 512) {
            int r = i >> 4, c = i & 15;
            int row = row0 + r;
            if (row < n) {
                uint2 a2 = *(const uint2*)&zs[r * PQ2 + c * 8];
                uint2 b2v = *(const uint2*)&zs[r * PQ2 + c * 8 + 4];
                ((uint4*)hout)[row * 16 + c] = make_uint4(a2.x, a2.y, b2v.x, b2v.y);
            }
        }
    } else {
        // pool epilogue from LDS tile (batch sorted)
        int c2 = tid & 63;      // uint column (ch 2*c2, 2*c2+1)
        int rs = tid >> 6;      // 0..7
        float a0 = 0.f, a1 = 0.f;
        int prevg = -1;
        #pragma unroll
        for (int i = 0; i < FBM / 8; ++i) {
            int r = rs + 8 * i;
            int row = row0 + r;
            if (row >= n) break;
            int g = batch[row];
            if (g != prevg) {
                if (prevg >= 0) {
                    atomicAdd(&pooled[prevg * CH + 2 * c2], a0);
                    atomicAdd(&pooled[prevg * CH + 2 * c2 + 1], a1);
                }
                prevg = g; a0 = 0.f; a1 = 0.f;
            }
            unsigned v = *(const unsigned*)&zs[r * PQ2 + c2 * 2];
            a0 += bflo(v); a1 += bfhi(v);
        }
        if (prevg >= 0) {
            atomicAdd(&pooled[prevg * CH + 2 * c2], a0);
            atomicAdd(&pooled[prevg * CH + 2 * c2 + 1], a1);
        }
    }
}

// ---------------------------------------------------------------- final linear

__global__ void final_linear_kernel(const float* __restrict__ pooled, const float* __restrict__ lin_w,
                                    const float* __restrict__ lin_b, float* __restrict__ out) {
    int g = blockIdx.x;
    int tid = threadIdx.x;   // 128
    __shared__ float pl[CH];
    pl[tid] = pooled[g * CH + tid];
    __syncthreads();
    if (tid < OUTC) {
        float a = lin_b[tid];
        #pragma unroll 16
        for (int c = 0; c < CH; ++c) a = fmaf(pl[c], lin_w[c * OUTC + tid], a);
        out[g * OUTC + tid] = a;
    }
}

// ---------------------------------------------------------------- launch

static inline size_t aln(size_t x) { return (x + 255) & ~size_t(255); }

extern "C" void kernel_launch(void* const* d_in, const int* in_sizes, int n_in,
                              void* d_out, int out_size, void* d_ws, size_t ws_size,
                              hipStream_t stream) {
    const float* x      = (const float*)d_in[0];
    const int*   ei     = (const int*)d_in[1];
    const int*   batch  = (const int*)d_in[2];
    const float* w1[3]  = {(const float*)d_in[3], (const float*)d_in[7],  (const float*)d_in[11]};
    const float* b1[3]  = {(const float*)d_in[4], (const float*)d_in[8],  (const float*)d_in[12]};
    const float* w2[3]  = {(const float*)d_in[5], (const float*)d_in[9],  (const float*)d_in[13]};
    const float* b2[3]  = {(const float*)d_in[6], (const float*)d_in[10], (const float*)d_in[14]};
    const float* lin_w  = (const float*)d_in[15];
    const float* lin_b  = (const float*)d_in[16];
    float* out = (float*)d_out;

    int E = in_sizes[1] / 2;
    int N = in_sizes[2];
    int n_graphs = out_size / OUTC;
    const int* src = ei;
    const int* dst = ei + E;

    char* p = (char*)d_ws;
    int* bucketCnt  = (int*)p; p += aln(NB2 * 4);
    unsigned* pairs = (unsigned*)p; p += aln((size_t)NB2 * BCAP2 * 4);
    int* offs       = (int*)p; p += aln((size_t)(N + 1) * 4);
    int* csr        = (int*)p; p += aln((size_t)E * 4);
    unsigned short* xb = (unsigned short*)p; p += aln((size_t)N * CH * 2);
    unsigned short* hA = (unsigned short*)p; p += aln((size_t)N * CH * 2);
    unsigned short* hB = (unsigned short*)p; p += aln((size_t)N * CH * 2);
    float* pooled = (float*)p; p += aln((size_t)n_graphs * CH * 4);
    unsigned short* wt[6];
    for (int i = 0; i < 6; ++i) { wt[i] = (unsigned short*)p; p += aln((size_t)CH * CH * 2); }
    (void)ws_size; (void)n_in;

    // bucketCnt must be zero before partition blocks run
    hipMemsetAsync(bucketCnt, 0, NB2 * 4, stream);

    // mega-prep: partition + convert x + swizzle weights + zero pooled
    int n4 = N * CH / 4;
    int nConvBlk = (n4 + 255) / 256;
    int nPartBlk = (E + PCHUNK - 1) / PCHUNK;
    int nPooled4 = n_graphs * CH / 4;
    int nZeroBlk = (nPooled4 + 255) / 256;
    WPtrs wp;
    for (int l = 0; l < 3; ++l) {
        wp.s[2 * l] = w1[l];     wp.d[2 * l] = wt[2 * l];
        wp.s[2 * l + 1] = w2[l]; wp.d[2 * l + 1] = wt[2 * l + 1];
    }
    prep_part_kernel<<<nPartBlk + nConvBlk + 384 + nZeroBlk, 256, 0, stream>>>(
        src, dst, bucketCnt, pairs, E, nPartBlk,
        (const float4*)x, (uint2*)xb, n4, nConvBlk, wp,
        (uint4*)pooled, nPooled4);

    build_csr_kernel<<<NB2, 512, 0, stream>>>(pairs, bucketCnt, offs, csr, N);

    int fblk = (N + FBM - 1) / FBM;

    // three fused GIN layers
    fused_gin_kernel<0, 1, 0><<<fblk, 512, 0, stream>>>((const uint4*)xb, offs, csr,
        wt[0], b1[0], wt[1], b2[0], hA, batch, pooled, N);
    fused_gin_kernel<1, 1, 0><<<fblk, 512, 0, stream>>>((const uint4*)hA, offs, csr,
        wt[2], b1[1], wt[3], b2[1], hB, batch, pooled, N);
    fused_gin_kernel<2, 0, 1><<<fblk, 512, 0, stream>>>((const uint4*)hB, offs, csr,
        wt[4], b1[2], wt[5], b2[2], (unsigned short*)nullptr, batch, pooled, N);

    final_linear_kernel<<<n_graphs, CH, 0, stream>>>(pooled, lin_w, lin_b, out);
}